// Round 5
// baseline (185.291 us; speedup 1.0000x reference)
//
#include <hip/hip_runtime.h>
#include <hip/hip_bf16.h>
#include <stdint.h>
#include <math.h>

// Problem constants (fixed by setup_inputs)
#define BATCH 8192   // B rows of embeddings
#define DIM   2048   // D feature dim
#define KDIR  512    // K directions
#define NPTS  17     // quadrature points

typedef _Float16 half8  __attribute__((ext_vector_type(8)));
typedef float   floatx4 __attribute__((ext_vector_type(4)));

#define AS1 __attribute__((address_space(1)))
#define AS3 __attribute__((address_space(3)))

// async global->LDS, 16B per lane. LDS dest must be wave-uniform base + lane*16.
__device__ __forceinline__ void g2l16(const void* g, void* l) {
    __builtin_amdgcn_global_load_lds((AS1 void*)(uintptr_t)g, (AS3 void*)l, 16u, 0, 0u);
}

// ---------------------------------------------------------------------------
// K1: PREP: dir normalize+transpose -> dT (fp16) + zero pp/out.
__global__ __launch_bounds__(256) void prep(const float* __restrict__ dir,
                                            _Float16* __restrict__ dT,
                                            float* __restrict__ pp,
                                            float* __restrict__ out) {
    const int b = blockIdx.x;   // 0..63
    const int t = threadIdx.x;
    if (b == 0) {
        ((floatx4*)pp)[t] = floatx4{0.f, 0.f, 0.f, 0.f};   // 1024 floats
        if (t == 0) out[0] = 0.f;
    }
    const int k0 = b * 8;
    __shared__ _Float16 sv[8][2052];    // [col][row] staged values (fp16)
    __shared__ float    sred[8][32];
    __shared__ float    sinv[8];
    const int g  = t >> 3;     // 0..31 row-group
    const int cl = t & 7;      // col within 8
    float ss = 0.f;
    #pragma unroll 8
    for (int it = 0; it < 64; ++it) {
        const int r = it * 32 + g;
        float v = dir[(size_t)r * KDIR + k0 + cl];   // 8 lanes = 32B contiguous
        sv[cl][r] = (_Float16)v;
        ss = fmaf(v, v, ss);
    }
    sred[cl][g] = ss;
    __syncthreads();
    if (t < 8) {
        float s = 0.f;
        #pragma unroll
        for (int gg = 0; gg < 32; ++gg) s += sred[t][gg];
        sinv[t] = 1.0f / fmaxf(sqrtf(s), 1e-12f);
    }
    __syncthreads();
    const int c2 = t >> 5;     // 0..7 col
    const int p  = t & 31;
    const float inv = sinv[c2];
    #pragma unroll
    for (int it2 = 0; it2 < 8; ++it2) {
        const int i0 = p * 8 + it2 * 256;
        half8 h;
        #pragma unroll
        for (int e = 0; e < 8; ++e) h[e] = (_Float16)((float)sv[c2][i0 + e] * inv);
        *(half8*)(dT + (size_t)(k0 + c2) * DIM + i0) = h;
    }
}

// ---------------------------------------------------------------------------
// K2: fp16 MFMA GEMM, restructured for stall overlap (round-3 counters:
// MfmaUtil 10%, all pipes idle -> structural stalls at 1 block/CU).
//   - Block tile 64(M) x 128(N), 128 threads = 2 waves, wave tile 64x64
//     (acc[4][4]): LDS-reads-per-MFMA ratio 0.5 (was 0.75).
//   - Grid (128,4) = 512 blocks = 2 independent blocks/CU: each block's
//     barrier/latency stalls overlap the other block's compute.
//   - K_STEP=32, 3 LDS stages (36KB): B staged 2 iters ahead via g2l16;
//     A fp32->regs (issued 1 full iter before drain) -> cvt fp16 ->
//     ds_write 2 iters ahead. No in-iteration HBM-latency exposure.
//   - Counted vmcnt: per iter exactly [4 A-loads, 4 B-g2l16] enter the
//     queue in pinned order; vmcnt(8) drains B(it+1), vmcnt(4) drains
//     A(it+2). Order pin between LOADA and ISSUEB (round-3-validated).
//   - 64B LDS rows: frag-read is a bijection within each 1KB group
//     (round-3 measured: conflicts only 2.7% of cycles) -> no swizzle.
//   - XCD remap: 512 blocks (512%8==0, bijective), d&7 owns 16
//     row-panels x 4 col-blocks -> A-panel consumed within one XCD.
__global__ __launch_bounds__(128) void gemm16(const float* __restrict__ A,
                                              const _Float16* __restrict__ Bt,
                                              _Float16* __restrict__ C,
                                              float* __restrict__ pp) {
    __shared__ __align__(16) _Float16 sA[3][64 * 32];    // 4KB/stage
    __shared__ __align__(16) _Float16 sB[3][128 * 32];   // 8KB/stage

    const int tid  = threadIdx.x;   // 0..127
    const int lane = tid & 63;
    const int wn   = tid >> 6;      // 0..1: 64-col half of the 128-col tile

    const int d    = blockIdx.x + 128 * blockIdx.y;
    const int xcd  = d & 7;
    const int slot = d >> 3;                  // 0..63
    const int bx   = xcd * 16 + (slot >> 2);  // 0..127 row-panel (64 rows)
    const int by   = slot & 3;                // 0..3   col-block (128 cols)
    const int tm   = bx * 64;
    const int tn   = by * 128;

    // A staging: 2 threads/row, 16 consecutive floats each
    const int arow = tid >> 1;              // 0..63
    const int akh  = (tid & 1) * 16;        // float col base
    const float* baseA = A + (size_t)(tm + arow) * DIM + akh;
    const int aoff0 = arow * 64 + akh * 2;  // byte offset in sA stage
    const int aoff1 = aoff0 + 16;

    // B staging (g2l16): 4 row-groups of 32; linear LDS dest
    const int brow = tid >> 2;              // 0..31
    const int bcol = (tid & 3) * 8;         // halfs
    const _Float16* baseB = Bt + (size_t)(tn + brow) * DIM + bcol;

    floatx4 rA0, rA1, rA2, rA3;

#define LOADA(IT) do {                                                        \
        const float* pa = baseA + (IT) * 32;                                  \
        rA0 = *(const floatx4*)(pa);      rA1 = *(const floatx4*)(pa + 4);    \
        rA2 = *(const floatx4*)(pa + 8);  rA3 = *(const floatx4*)(pa + 12);   \
        asm volatile("" ::: "memory");  /* pin: A-loads before B g2l16s */    \
    } while (0)

#define ISSUEB(IT, ST) do {                                                   \
        const _Float16* pb = baseB + (IT) * 32;                               \
        char* lb = (char*)&sB[0][0] + (ST) * 8192 + tid * 16;                 \
        g2l16(pb,            lb);                                             \
        g2l16(pb + 32 * DIM, lb + 2048);                                      \
        g2l16(pb + 64 * DIM, lb + 4096);                                      \
        g2l16(pb + 96 * DIM, lb + 6144);                                      \
    } while (0)

#define WRITEA(ST) do {                                                       \
        half8 h0, h1;                                                         \
        h0[0] = (_Float16)rA0[0]; h0[1] = (_Float16)rA0[1];                   \
        h0[2] = (_Float16)rA0[2]; h0[3] = (_Float16)rA0[3];                   \
        h0[4] = (_Float16)rA1[0]; h0[5] = (_Float16)rA1[1];                   \
        h0[6] = (_Float16)rA1[2]; h0[7] = (_Float16)rA1[3];                   \
        h1[0] = (_Float16)rA2[0]; h1[1] = (_Float16)rA2[1];                   \
        h1[2] = (_Float16)rA2[2]; h1[3] = (_Float16)rA2[3];                   \
        h1[4] = (_Float16)rA3[0]; h1[5] = (_Float16)rA3[1];                   \
        h1[6] = (_Float16)rA3[2]; h1[7] = (_Float16)rA3[3];                   \
        char* la = (char*)&sA[0][0] + (ST) * 4096;                            \
        *(half8*)(la + aoff0) = h0;                                           \
        *(half8*)(la + aoff1) = h1;                                           \
    } while (0)

    const floatx4 zero = {0.f, 0.f, 0.f, 0.f};
    floatx4 acc[4][4];
    #pragma unroll
    for (int i = 0; i < 4; ++i)
        #pragma unroll
        for (int j = 0; j < 4; ++j) acc[i][j] = zero;

    const int mrow = lane & 15;
    const int kk   = (lane >> 4) * 8;       // half-index 0/8/16/24

    // ---- prologue: establish invariant (entering it=0):
    //   st0 = A(0)+B(0) complete; st1 = A(1) written, B(1) in flight;
    //   regs hold A(2) in flight; queue = [B(1) x4, A(2) x4]
    LOADA(0);
    ISSUEB(0, 0);                                     // [A0 4, B0 4]
    asm volatile("s_waitcnt vmcnt(4)" ::: "memory");  // A0 regs ready
    WRITEA(0);
    LOADA(1);
    ISSUEB(1, 1);                                     // [B0 4, A1 4, B1 4]
    asm volatile("s_waitcnt vmcnt(4)" ::: "memory");  // retire B0 + A1
    WRITEA(1);
    LOADA(2);                                         // [B1 4, A2 4]
    asm volatile("s_waitcnt lgkmcnt(0)" ::: "memory");
    asm volatile("s_barrier" ::: "memory");

    const int NIT = DIM / 32;                         // 64
    for (int it = 0; it < NIT; ++it) {
        const int s = it % 3;
        if (it + 2 < NIT) {
            ISSUEB(it + 2, (it + 2) % 3);             // [B(it+1), A(it+2), B(it+2)]
            asm volatile("s_waitcnt vmcnt(8)" ::: "memory");  // drain B(it+1)
        } else {
            asm volatile("s_waitcnt vmcnt(0)" ::: "memory");
        }
        asm volatile("s_barrier" ::: "memory");       // stage s fully visible

        half8 a[4], b[4];
        #pragma unroll
        for (int f = 0; f < 4; ++f)
            a[f] = *(const half8*)(&sA[0][0] + s * 2048 + (size_t)(f * 16 + mrow) * 32 + kk);
        #pragma unroll
        for (int f = 0; f < 4; ++f)
            b[f] = *(const half8*)(&sB[0][0] + s * 4096 + (size_t)(wn * 64 + f * 16 + mrow) * 32 + kk);

        #pragma unroll
        for (int i = 0; i < 4; ++i)
            #pragma unroll
            for (int j = 0; j < 4; ++j)
                acc[i][j] = __builtin_amdgcn_mfma_f32_16x16x32_f16(a[i], b[j], acc[i][j], 0, 0, 0);

        if (it + 2 < NIT) {
            // queue: [A(it+2) x4, B(it+2) x4]; drain A only.
            asm volatile("s_waitcnt vmcnt(4)" ::: "memory");
            WRITEA((it + 2) % 3);                     // stage (it+2)%3 != s
            if (it + 3 < NIT) LOADA(it + 3);          // full-iter slack to drain
        }
        asm volatile("s_waitcnt lgkmcnt(0)" ::: "memory"); // reads(s)+A-writes done
        asm volatile("s_barrier" ::: "memory");
    }
#undef LOADA
#undef ISSUEB
#undef WRITEA

    // C/D layout: col = lane&15, row = (lane>>4)*4 + reg. fp16 stores.
    const int r0 = (lane >> 4) * 4;
    const int cn = lane & 15;
    #pragma unroll
    for (int i = 0; i < 4; ++i) {
        #pragma unroll
        for (int j = 0; j < 4; ++j) {
            const int row = tm + i * 16 + r0;
            const int col = tn + wn * 64 + j * 16 + cn;
            #pragma unroll
            for (int r = 0; r < 4; ++r)
                C[(size_t)(row + r) * KDIR + col] = (_Float16)acc[i][j][r];
        }
    }

    // fused column stats; each wave covers all 64 block rows per column
    #pragma unroll
    for (int j = 0; j < 4; ++j) {
        float s = 0.f, q = 0.f;
        #pragma unroll
        for (int i = 0; i < 4; ++i)
            #pragma unroll
            for (int r = 0; r < 4; ++r) {
                float v = acc[i][j][r];
                s += v;
                q = fmaf(v, v, q);
            }
        s += __shfl_down(s, 32, 64); q += __shfl_down(q, 32, 64);
        s += __shfl_down(s, 16, 64); q += __shfl_down(q, 16, 64);
        if (lane < 16) {
            const int col = tn + wn * 64 + j * 16 + lane;
            atomicAdd(&pp[col], s);
            atomicAdd(&pp[KDIR + col], q);
        }
    }
}

// ---------------------------------------------------------------------------
// K3: ECF partials. Native v_sin_f32/v_cos_f32 (input in revolutions;
// |a| <= ~0.7 rad so no range reduction needed).
__global__ __launch_bounds__(256) void ecf_p1(const _Float16* __restrict__ proj,
                                              const float* __restrict__ pp,
                                              float* __restrict__ pecf) {
    const int ch = blockIdx.x >> 1;                      // 0..255
    const int c  = (blockIdx.x & 1) * 256 + threadIdx.x; // 0..511
    const double s_  = (double)pp[c];
    const double s2_ = (double)pp[KDIR + c];
    const double mm  = s_ / (double)BATCH;
    const double var = (s2_ - (double)BATCH * mm * mm) / (double)(BATCH - 1);
    const float m   = (float)mm;
    const float sdi = (float)(1.0 / (sqrt(var) + 1e-8));

    float cr[NPTS], ci[NPTS];
    #pragma unroll
    for (int i = 0; i < NPTS; ++i) { cr[i] = 0.f; ci[i] = 0.f; }
    const _Float16* p = proj + (size_t)(ch * 32) * KDIR + c;
    #pragma unroll 8
    for (int r = 0; r < 32; ++r) {
        float z = ((float)p[(size_t)r * KDIR] - m) * sdi;
        float a = z * (2.0f / 17.0f);                    // t_1 * z (radians)
        const float rev = a * 0.15915494309189535f;      // a / (2*pi)
        float s1 = __builtin_amdgcn_sinf(rev);           // v_sin_f32
        float c1 = __builtin_amdgcn_cosf(rev);           // v_cos_f32
        const float tc = 2.0f * c1;
        float cm = 1.0f, sm = 0.0f;
        float ck = c1,  sk = s1;
        cr[0] += ck; ci[0] += sk;
        #pragma unroll
        for (int k = 1; k < NPTS; ++k) {
            float cn_ = fmaf(tc, ck, -cm);
            float sn_ = fmaf(tc, sk, -sm);
            cm = ck; sm = sk;
            ck = cn_; sk = sn_;
            cr[k] += ck; ci[k] += sk;
        }
    }
    #pragma unroll
    for (int i = 0; i < NPTS; ++i) {
        pecf[(size_t)((ch * NPTS + i) * 2 + 0) * KDIR + c] = cr[i];
        pecf[(size_t)((ch * NPTS + i) * 2 + 1) * KDIR + c] = ci[i];
    }
}

// K4: chunk reduce (unchanged)
__global__ __launch_bounds__(256) void ecf_p2a(const float* __restrict__ pecf,
                                               double* __restrict__ pec2) {
    const int b = blockIdx.x;
    const int i = b >> 5;                 // 0..16
    const int r = b & 31;
    const int g = r >> 1;                 // 0..15
    const int half = r & 1;
    const int c = half * 256 + threadIdx.x;
    double sc = 0.0, ss = 0.0;
    #pragma unroll
    for (int k = 0; k < 16; ++k) {
        const int ch = g * 16 + k;
        sc += (double)pecf[(size_t)((ch * NPTS + i) * 2 + 0) * KDIR + c];
        ss += (double)pecf[(size_t)((ch * NPTS + i) * 2 + 1) * KDIR + c];
    }
    pec2[(size_t)((i * 16 + g) * 2 + 0) * KDIR + c] = sc;
    pec2[(size_t)((i * 16 + g) * 2 + 1) * KDIR + c] = ss;
}

// K5: finish (unchanged)
__global__ __launch_bounds__(256) void ecf_p2b(const double* __restrict__ pec2,
                                               float* __restrict__ out) {
    const int i = blockIdx.x >> 1;
    const int c = (blockIdx.x & 1) * 256 + threadIdx.x;
    double sc = 0.0, ss = 0.0;
    #pragma unroll
    for (int g = 0; g < 16; ++g) {
        sc += pec2[(size_t)((i * 16 + g) * 2 + 0) * KDIR + c];
        ss += pec2[(size_t)((i * 16 + g) * 2 + 1) * KDIR + c];
    }
    const double R = sc / (double)BATCH;
    const double I = ss / (double)BATCH;
    const double t = (2.0 / 17.0) * (double)(i + 1);
    const double tau = exp(-0.5 * t * t);
    const double w = (i == 0 || i == NPTS - 1) ? (1.0 / 17.0) : (2.0 / 17.0);
    const double dR = R - tau;
    double contrib = w * (dR * dR + I * I) / (double)KDIR;

    __shared__ double red[256];
    red[threadIdx.x] = contrib;
    __syncthreads();
    for (int s = 128; s > 0; s >>= 1) {
        if (threadIdx.x < s) red[threadIdx.x] += red[threadIdx.x + s];
        __syncthreads();
    }
    if (threadIdx.x == 0) atomicAdd(out, (float)red[0]);
}

// ---------------------------------------------------------------------------
extern "C" void kernel_launch(void* const* d_in, const int* in_sizes, int n_in,
                              void* d_out, int out_size, void* d_ws, size_t ws_size,
                              hipStream_t stream) {
    const float* emb = (const float*)d_in[0];   // (8192, 2048) fp32
    const float* dir = (const float*)d_in[1];   // (2048, 512) fp32
    float* out = (float*)d_out;

    char* ws = (char*)d_ws;
    float*    pecf = (float*)   (ws + 0);               // 17,825,792 B
    double*   pec2 = (double*)  (ws + 17825792);        //  2,228,224 B
    _Float16* dT   = (_Float16*)(ws + 33554432);        //  2,097,152 B
    _Float16* proj = (_Float16*)(ws + 35651584);        //  8,388,608 B
    float*    pp   = (float*)   (ws + 44040192);        //      4,096 B

    prep<<<64, 256, 0, stream>>>(dir, dT, pp, out);
    gemm16<<<dim3(128, 4), 128, 0, stream>>>(emb, dT, proj, pp);
    ecf_p1<<<512, 256, 0, stream>>>(proj, pp, pecf);
    ecf_p2a<<<544, 256, 0, stream>>>(pecf, pec2);
    ecf_p2b<<<34, 256, 0, stream>>>(pec2, out);
}

// Round 6
// 176.299 us; speedup vs baseline: 1.0510x; 1.0510x over previous
//
#include <hip/hip_runtime.h>
#include <hip/hip_bf16.h>
#include <stdint.h>
#include <math.h>

// Problem constants (fixed by setup_inputs)
#define BATCH 8192   // B rows of embeddings
#define DIM   2048   // D feature dim
#define KDIR  512    // K directions
#define NPTS  17     // quadrature points

typedef _Float16 half8  __attribute__((ext_vector_type(8)));
typedef float   floatx4 __attribute__((ext_vector_type(4)));

#define AS1 __attribute__((address_space(1)))
#define AS3 __attribute__((address_space(3)))

// async global->LDS, 16B per lane. LDS dest must be wave-uniform base + lane*16.
__device__ __forceinline__ void g2l16(const void* g, void* l) {
    __builtin_amdgcn_global_load_lds((AS1 void*)(uintptr_t)g, (AS3 void*)l, 16u, 0, 0u);
}

// ---------------------------------------------------------------------------
// K1: PREP: dir normalize+transpose -> dT (fp16) + zero pp/out. (unchanged)
__global__ __launch_bounds__(256) void prep(const float* __restrict__ dir,
                                            _Float16* __restrict__ dT,
                                            float* __restrict__ pp,
                                            float* __restrict__ out) {
    const int b = blockIdx.x;   // 0..63
    const int t = threadIdx.x;
    if (b == 0) {
        ((floatx4*)pp)[t] = floatx4{0.f, 0.f, 0.f, 0.f};   // 1024 floats
        if (t == 0) out[0] = 0.f;
    }
    const int k0 = b * 8;
    __shared__ _Float16 sv[8][2052];    // [col][row] staged values (fp16)
    __shared__ float    sred[8][32];
    __shared__ float    sinv[8];
    const int g  = t >> 3;     // 0..31 row-group
    const int cl = t & 7;      // col within 8
    float ss = 0.f;
    #pragma unroll 8
    for (int it = 0; it < 64; ++it) {
        const int r = it * 32 + g;
        float v = dir[(size_t)r * KDIR + k0 + cl];   // 8 lanes = 32B contiguous
        sv[cl][r] = (_Float16)v;
        ss = fmaf(v, v, ss);
    }
    sred[cl][g] = ss;
    __syncthreads();
    if (t < 8) {
        float s = 0.f;
        #pragma unroll
        for (int gg = 0; gg < 32; ++gg) s += sred[t][gg];
        sinv[t] = 1.0f / fmaxf(sqrtf(s), 1e-12f);
    }
    __syncthreads();
    const int c2 = t >> 5;     // 0..7 col
    const int p  = t & 31;
    const float inv = sinv[c2];
    #pragma unroll
    for (int it2 = 0; it2 < 8; ++it2) {
        const int i0 = p * 8 + it2 * 256;
        half8 h;
        #pragma unroll
        for (int e = 0; e < 8; ++e) h[e] = (_Float16)((float)sv[c2][i0 + e] * inv);
        *(half8*)(dT + (size_t)(k0 + c2) * DIM + i0) = h;
    }
}

// ---------------------------------------------------------------------------
// K2: fp16 MFMA GEMM. Measured-driven redesign (r0/r3/r5 data: time tracks
// BARRIER FREQUENCY — orig 2bar/64K=45.6us, r3 2bar/32K=62us, r5 ditto=83us):
//   - 256 threads / 128x128 tile (the proven-45.6 shape), K_STEP=64.
//   - THREE LDS stages, ONE barrier per K-step (32 total, was 64/128):
//     write target (it+2)%3 == (it-1)%3 is freed by the top barrier, so the
//     read-protect barrier is unnecessary. lgkmcnt(0) before the barrier
//     publishes each wave's A-writes.
//   - Counted vmcnt ledger (order-pinned, r3-validated): per iter issue
//     [A(it+2) regs x8, B(it+2) g2l16 x4]; vmcnt(12) drains B(it+1) at top;
//     vmcnt(4) drains A-regs post-MFMA; B stays in flight across barriers.
//   - Bank conflicts (r5: 3.1M cycles at 64B rows): 128B rows + XOR-slot
//     swizzle on BOTH operands -> 2-way (free). B keeps linear g2l16 dest
//     with PRE-SWIZZLED global source (m173 pattern; legal: row&7 is
//     invariant across a thread's 4 row-chunks). A is reg-staged, writes
//     swizzled directly.
//   - fp32 A read directly (no A16 prepass): 64MB total vs 128MB.
//   - XCD remap: 256 blocks (%8==0, bijective), d&7 owns 8 row-panels x 4
//     col-blocks -> A-panel consumed within one XCD.
__global__ __launch_bounds__(256, 1) void gemm16(const float* __restrict__ A,
                                                 const _Float16* __restrict__ Bt,
                                                 _Float16* __restrict__ C,
                                                 float* __restrict__ pp) {
    __shared__ __align__(16) _Float16 sA[3][128 * 64];   // 16KB/stage
    __shared__ __align__(16) _Float16 sB[3][128 * 64];   // 16KB/stage (96KB tot)

    const int tid  = threadIdx.x;   // 0..255
    const int lane = tid & 63;
    const int wave = tid >> 6;      // 0..3
    const int wm   = wave & 1;      // 2x2 wave grid, wave tile 64x64
    const int wn   = wave >> 1;

    const int d    = blockIdx.x + 64 * blockIdx.y;   // grid (64,4) = 256
    const int xcd  = d & 7;
    const int slot = d >> 3;                 // 0..31
    const int bx   = xcd * 8 + (slot >> 2);  // 0..63 row-panel (128 rows)
    const int by   = slot & 3;               // 0..3  col-block (128 cols)
    const int tm   = bx * 128;
    const int tn   = by * 128;

    // A staging: 2 threads/row, 32 consecutive floats each (8x dwordx4)
    const int arow = tid >> 1;               // 0..127
    const int acb  = (tid & 1) * 32;         // float col base in K64
    const float* baseA = A + (size_t)(tm + arow) * DIM + acb;
    const int asw = arow & 7;
    int awoff[4];                            // swizzled 16B-slot write offsets
    #pragma unroll
    for (int i = 0; i < 4; ++i)
        awoff[i] = arow * 128 + ((((tid & 1) * 4 + i) ^ asw) << 4);

    // B staging: linear g2l16 dest; swizzle via global source slot.
    // Linear dest row = 32*round + (tid>>3), slot = tid&7; row&7 = (tid>>3)&7.
    const int brow0 = tid >> 3;              // 0..31
    const int bslot = (tid & 7) ^ (brow0 & 7);
    const _Float16* baseB = Bt + (size_t)(tn + brow0) * DIM + bslot * 8;

    floatx4 rA[8];

#define LOADA(IT) do {                                                        \
        const float* pa = baseA + (IT) * 64;                                  \
        _Pragma("unroll")                                                     \
        for (int q = 0; q < 8; ++q) rA[q] = *(const floatx4*)(pa + q * 4);    \
        asm volatile("" ::: "memory");  /* pin: A-loads before B g2l16s */    \
    } while (0)

#define ISSUEB(IT, ST) do {                                                   \
        const _Float16* pb = baseB + (IT) * 64;                               \
        char* lb = (char*)&sB[0][0] + (ST) * 16384 + tid * 16;                \
        g2l16(pb,            lb);                                             \
        g2l16(pb + 32 * DIM, lb + 4096);                                      \
        g2l16(pb + 64 * DIM, lb + 8192);                                      \
        g2l16(pb + 96 * DIM, lb + 12288);                                     \
    } while (0)

#define WRITEA(ST) do {                                                       \
        char* la = (char*)&sA[0][0] + (ST) * 16384;                           \
        _Pragma("unroll")                                                     \
        for (int i = 0; i < 4; ++i) {                                         \
            half8 h;                                                          \
            h[0] = (_Float16)rA[2*i][0]; h[1] = (_Float16)rA[2*i][1];         \
            h[2] = (_Float16)rA[2*i][2]; h[3] = (_Float16)rA[2*i][3];         \
            h[4] = (_Float16)rA[2*i+1][0]; h[5] = (_Float16)rA[2*i+1][1];     \
            h[6] = (_Float16)rA[2*i+1][2]; h[7] = (_Float16)rA[2*i+1][3];     \
            *(half8*)(la + awoff[i]) = h;                                     \
        }                                                                     \
    } while (0)

    const floatx4 zero = {0.f, 0.f, 0.f, 0.f};
    floatx4 acc[4][4];
    #pragma unroll
    for (int i = 0; i < 4; ++i)
        #pragma unroll
        for (int j = 0; j < 4; ++j) acc[i][j] = zero;

    const int mrow = lane & 15;
    const int g4   = lane >> 4;              // 0..3 k-subgroup
    const int rsw  = mrow & 7;               // read swizzle (row&7 == mrow&7)
    // frag byte offsets within a stage: row*128 + ((ks*4+g4)^rsw)*16
    const int sl0  = ((0 * 4 + g4) ^ rsw) << 4;   // ks=0
    const int sl1  = ((1 * 4 + g4) ^ rsw) << 4;   // ks=1

    // ---- prologue ----
    LOADA(0); ISSUEB(0, 0);                           // [A0 x8, B0 x4]
    asm volatile("s_waitcnt vmcnt(4)" ::: "memory");  // drain A0 (B0 in flight)
    WRITEA(0);
    LOADA(1); ISSUEB(1, 1);                           // [B0 4, A1 8, B1 4]
    asm volatile("s_waitcnt vmcnt(4)" ::: "memory");  // drain B0 + A1
    WRITEA(1);
    asm volatile("s_waitcnt lgkmcnt(0)" ::: "memory");

    const int NIT = DIM / 64;                         // 32
    for (int it = 0; it < NIT; ++it) {
        const int s = it % 3;
        if (it + 2 < NIT) {
            LOADA(it + 2);
            ISSUEB(it + 2, (it + 2) % 3);
            // outstanding: [B(it+1) 4, A(it+2) 8, B(it+2) 4] = 16
            asm volatile("s_waitcnt vmcnt(12)" ::: "memory");  // drain B(it+1)
        } else {
            asm volatile("s_waitcnt vmcnt(0)" ::: "memory");
        }
        asm volatile("s_barrier" ::: "memory");       // ONE barrier per K-step

        const char* la = (char*)&sA[0][0] + s * 16384;
        const char* lb = (char*)&sB[0][0] + s * 16384;
        half8 a[4][2], b[4][2];
        #pragma unroll
        for (int f = 0; f < 4; ++f) {
            const int ra = (wm * 64 + f * 16 + mrow) * 128;
            const int rb = (wn * 64 + f * 16 + mrow) * 128;
            a[f][0] = *(const half8*)(la + ra + sl0);
            a[f][1] = *(const half8*)(la + ra + sl1);
            b[f][0] = *(const half8*)(lb + rb + sl0);
            b[f][1] = *(const half8*)(lb + rb + sl1);
        }
        #pragma unroll
        for (int ks = 0; ks < 2; ++ks)
            #pragma unroll
            for (int i = 0; i < 4; ++i)
                #pragma unroll
                for (int j = 0; j < 4; ++j)
                    acc[i][j] = __builtin_amdgcn_mfma_f32_16x16x32_f16(a[i][ks], b[j][ks], acc[i][j], 0, 0, 0);

        if (it + 2 < NIT) {
            // outstanding: [A(it+2) 8, B(it+2) 4]; drain A only.
            asm volatile("s_waitcnt vmcnt(4)" ::: "memory");
            WRITEA((it + 2) % 3);                     // == (it-1)%3, freed by barrier
        }
        asm volatile("s_waitcnt lgkmcnt(0)" ::: "memory");  // publish A-writes
    }
#undef LOADA
#undef ISSUEB
#undef WRITEA

    // C/D layout: col = lane&15, row = (lane>>4)*4 + reg. fp16 stores.
    const int r0 = (lane >> 4) * 4;
    const int cn = lane & 15;
    #pragma unroll
    for (int i = 0; i < 4; ++i) {
        #pragma unroll
        for (int j = 0; j < 4; ++j) {
            const int row = tm + wm * 64 + i * 16 + r0;
            const int col = tn + wn * 64 + j * 16 + cn;
            #pragma unroll
            for (int r = 0; r < 4; ++r)
                C[(size_t)(row + r) * KDIR + col] = (_Float16)acc[i][j][r];
        }
    }

    // fused column stats (fp32 acc values); per wave: 64 rows per column
    #pragma unroll
    for (int j = 0; j < 4; ++j) {
        float s = 0.f, q = 0.f;
        #pragma unroll
        for (int i = 0; i < 4; ++i)
            #pragma unroll
            for (int r = 0; r < 4; ++r) {
                float v = acc[i][j][r];
                s += v;
                q = fmaf(v, v, q);
            }
        s += __shfl_down(s, 32, 64); q += __shfl_down(q, 32, 64);
        s += __shfl_down(s, 16, 64); q += __shfl_down(q, 16, 64);
        if (lane < 16) {
            const int col = tn + wn * 64 + j * 16 + lane;
            atomicAdd(&pp[col], s);
            atomicAdd(&pp[KDIR + col], q);
        }
    }
}

// ---------------------------------------------------------------------------
// K3: ECF partials. Native v_sin_f32/v_cos_f32 (input in revolutions;
// |a| <= ~0.7 rad so no range reduction needed).
__global__ __launch_bounds__(256) void ecf_p1(const _Float16* __restrict__ proj,
                                              const float* __restrict__ pp,
                                              float* __restrict__ pecf) {
    const int ch = blockIdx.x >> 1;                      // 0..255
    const int c  = (blockIdx.x & 1) * 256 + threadIdx.x; // 0..511
    const double s_  = (double)pp[c];
    const double s2_ = (double)pp[KDIR + c];
    const double mm  = s_ / (double)BATCH;
    const double var = (s2_ - (double)BATCH * mm * mm) / (double)(BATCH - 1);
    const float m   = (float)mm;
    const float sdi = (float)(1.0 / (sqrt(var) + 1e-8));

    float cr[NPTS], ci[NPTS];
    #pragma unroll
    for (int i = 0; i < NPTS; ++i) { cr[i] = 0.f; ci[i] = 0.f; }
    const _Float16* p = proj + (size_t)(ch * 32) * KDIR + c;
    #pragma unroll 8
    for (int r = 0; r < 32; ++r) {
        float z = ((float)p[(size_t)r * KDIR] - m) * sdi;
        float a = z * (2.0f / 17.0f);                    // t_1 * z (radians)
        const float rev = a * 0.15915494309189535f;      // a / (2*pi)
        float s1 = __builtin_amdgcn_sinf(rev);           // v_sin_f32
        float c1 = __builtin_amdgcn_cosf(rev);           // v_cos_f32
        const float tc = 2.0f * c1;
        float cm = 1.0f, sm = 0.0f;
        float ck = c1,  sk = s1;
        cr[0] += ck; ci[0] += sk;
        #pragma unroll
        for (int k = 1; k < NPTS; ++k) {
            float cn_ = fmaf(tc, ck, -cm);
            float sn_ = fmaf(tc, sk, -sm);
            cm = ck; sm = sk;
            ck = cn_; sk = sn_;
            cr[k] += ck; ci[k] += sk;
        }
    }
    #pragma unroll
    for (int i = 0; i < NPTS; ++i) {
        pecf[(size_t)((ch * NPTS + i) * 2 + 0) * KDIR + c] = cr[i];
        pecf[(size_t)((ch * NPTS + i) * 2 + 1) * KDIR + c] = ci[i];
    }
}

// K4: chunk reduce (unchanged)
__global__ __launch_bounds__(256) void ecf_p2a(const float* __restrict__ pecf,
                                               double* __restrict__ pec2) {
    const int b = blockIdx.x;
    const int i = b >> 5;                 // 0..16
    const int r = b & 31;
    const int g = r >> 1;                 // 0..15
    const int half = r & 1;
    const int c = half * 256 + threadIdx.x;
    double sc = 0.0, ss = 0.0;
    #pragma unroll
    for (int k = 0; k < 16; ++k) {
        const int ch = g * 16 + k;
        sc += (double)pecf[(size_t)((ch * NPTS + i) * 2 + 0) * KDIR + c];
        ss += (double)pecf[(size_t)((ch * NPTS + i) * 2 + 1) * KDIR + c];
    }
    pec2[(size_t)((i * 16 + g) * 2 + 0) * KDIR + c] = sc;
    pec2[(size_t)((i * 16 + g) * 2 + 1) * KDIR + c] = ss;
}

// K5: finish (unchanged)
__global__ __launch_bounds__(256) void ecf_p2b(const double* __restrict__ pec2,
                                               float* __restrict__ out) {
    const int i = blockIdx.x >> 1;
    const int c = (blockIdx.x & 1) * 256 + threadIdx.x;
    double sc = 0.0, ss = 0.0;
    #pragma unroll
    for (int g = 0; g < 16; ++g) {
        sc += pec2[(size_t)((i * 16 + g) * 2 + 0) * KDIR + c];
        ss += pec2[(size_t)((i * 16 + g) * 2 + 1) * KDIR + c];
    }
    const double R = sc / (double)BATCH;
    const double I = ss / (double)BATCH;
    const double t = (2.0 / 17.0) * (double)(i + 1);
    const double tau = exp(-0.5 * t * t);
    const double w = (i == 0 || i == NPTS - 1) ? (1.0 / 17.0) : (2.0 / 17.0);
    const double dR = R - tau;
    double contrib = w * (dR * dR + I * I) / (double)KDIR;

    __shared__ double red[256];
    red[threadIdx.x] = contrib;
    __syncthreads();
    for (int s = 128; s > 0; s >>= 1) {
        if (threadIdx.x < s) red[threadIdx.x] += red[threadIdx.x + s];
        __syncthreads();
    }
    if (threadIdx.x == 0) atomicAdd(out, (float)red[0]);
}

// ---------------------------------------------------------------------------
extern "C" void kernel_launch(void* const* d_in, const int* in_sizes, int n_in,
                              void* d_out, int out_size, void* d_ws, size_t ws_size,
                              hipStream_t stream) {
    const float* emb = (const float*)d_in[0];   // (8192, 2048) fp32
    const float* dir = (const float*)d_in[1];   // (2048, 512) fp32
    float* out = (float*)d_out;

    char* ws = (char*)d_ws;
    float*    pecf = (float*)   (ws + 0);               // 17,825,792 B
    double*   pec2 = (double*)  (ws + 17825792);        //  2,228,224 B
    _Float16* dT   = (_Float16*)(ws + 33554432);        //  2,097,152 B
    _Float16* proj = (_Float16*)(ws + 35651584);        //  8,388,608 B
    float*    pp   = (float*)   (ws + 44040192);        //      4,096 B

    prep<<<64, 256, 0, stream>>>(dir, dT, pp, out);
    gemm16<<<dim3(64, 4), 256, 0, stream>>>(emb, dT, proj, pp);
    ecf_p1<<<512, 256, 0, stream>>>(proj, pp, pecf);
    ecf_p2a<<<544, 256, 0, stream>>>(pecf, pec2);
    ecf_p2b<<<34, 256, 0, stream>>>(pec2, out);
}